// Round 15
// baseline (269.041 us; speedup 1.0000x reference)
//
#include <hip/hip_runtime.h>
#include <hip/hip_bf16.h>
#include <hip/hip_cooperative_groups.h>
#include <math.h>

namespace cg = cooperative_groups;

namespace {
constexpr int kB  = 64;
constexpr int kNi = 2048;
constexpr int kSeg   = 512;            // od = o*16 + d
constexpr int kSlabs = 256;            // n-slabs = grid = 1 block/CU
constexpr int kNPer  = kNi / kSlabs;   // 8 n per slab
}

typedef __attribute__((ext_vector_type(4)))  short s4;    // 4 bf16 (2 VGPR)
typedef __attribute__((ext_vector_type(16))) float f16v;  // MFMA C/D

__device__ __forceinline__ f16v mfma_32x32x8_bf16(s4 a, s4 b, f16v c) {
#if __has_builtin(__builtin_amdgcn_mfma_f32_32x32x8bf16_1k)
    return __builtin_amdgcn_mfma_f32_32x32x8bf16_1k(a, b, c, 0, 0, 0);
#else
    asm("v_mfma_f32_32x32x8_bf16 %0, %1, %2, %0" : "+v"(c) : "v"(a), "v"(b));
    return c;
#endif
}

__device__ __forceinline__ unsigned pack_bf16(float lo, float hi) {
    union { __hip_bfloat162 h; unsigned u; } v;
    v.h = __float22bfloat162_rn(make_float2(lo, hi));
    return v.u;
}
__device__ __forceinline__ float bf_lo(unsigned u) { return __uint_as_float(u << 16); }
__device__ __forceinline__ float bf_hi(unsigned u) { return __uint_as_float(u & 0xffff0000u); }

union A2 { int2 i; s4 s; };

// C/D layout (m74/m101-verified): col = l&31 (= b),
// row = (reg&3)+8*(reg>>2)+4*(l>>5); regs 0-7 -> o=2mt, regs 8-15 -> o=2mt+1.

// ---------------------------------------------------------------------------
// Phase bodies (all r14-verified logic, re-expressed as device functions).
// ---------------------------------------------------------------------------
__device__ void prepacc_body(const float* __restrict__ xg, const float* __restrict__ Wg,
                             unsigned* __restrict__ wPack2, unsigned* __restrict__ xPack,
                             __hip_bfloat16* __restrict__ partial)
{
    const int tid = threadIdx.x;
    const int blk = blockIdx.x;                    // slab 0..255
    const int w   = __builtin_amdgcn_readfirstlane(tid >> 6);
    const int l   = tid & 63;
    const int o32 = l & 31;
    const int hi  = l >> 5;

    const float4* Wg4 = reinterpret_cast<const float4*>(Wg);
    const float4* xg4 = reinterpret_cast<const float4*>(xg);

    f16v acc00, acc01, acc10, acc11;   // [nt][m], static names (rule #20)
#pragma unroll
    for (int r = 0; r < 16; ++r) {
        acc00[r] = 0.0f; acc01[r] = 0.0f; acc10[r] = 0.0f; acc11[r] = 0.0f;
    }

#pragma unroll 2
    for (int nn = 0; nn < kNPer; ++nn) {
        const int n = blk * kNPer + nn;
        const float4 w0 = Wg4[((size_t)n * 512 + (2 * w + 0) * 32 + o32) * 2 + hi];
        const float4 w1 = Wg4[((size_t)n * 512 + (2 * w + 1) * 32 + o32) * 2 + hi];
        int4 wp;
        wp.x = (int)pack_bf16(w0.x, w0.y);
        wp.y = (int)pack_bf16(w0.z, w0.w);
        wp.z = (int)pack_bf16(w1.x, w1.y);
        wp.w = (int)pack_bf16(w1.z, w1.w);
        reinterpret_cast<int4*>(wPack2)[((size_t)n * 8 + w) * 64 + l] = wp;

        const float4 x0 = xg4[((size_t)(0 * 32 + o32) * kNi + n) * 2 + hi];
        const float4 x1 = xg4[((size_t)(32 + o32) * kNi + n) * 2 + hi];
        uint2 q0, q1;
        q0.x = pack_bf16(x0.x, x0.y); q0.y = pack_bf16(x0.z, x0.w);
        q1.x = pack_bf16(x1.x, x1.y); q1.y = pack_bf16(x1.z, x1.w);
        *reinterpret_cast<uint2*>(xPack + ((size_t)(n * 2 + 0) * 64 + l) * 2) = q0;
        *reinterpret_cast<uint2*>(xPack + ((size_t)(n * 2 + 1) * 64 + l) * 2) = q1;

        A2 a0; a0.i = make_int2(wp.x, wp.y);
        A2 a1; a1.i = make_int2(wp.z, wp.w);
        A2 b0; b0.i = make_int2((int)q0.x, (int)q0.y);
        A2 b1; b1.i = make_int2((int)q1.x, (int)q1.y);
        acc00 = mfma_32x32x8_bf16(a0.s, b0.s, acc00);
        acc01 = mfma_32x32x8_bf16(a1.s, b0.s, acc01);
        acc10 = mfma_32x32x8_bf16(a0.s, b1.s, acc10);
        acc11 = mfma_32x32x8_bf16(a1.s, b1.s, acc11);
    }

#pragma unroll
    for (int nt = 0; nt < 2; ++nt) {
        const int b = nt * 32 + o32;
#pragma unroll
        for (int m = 0; m < 2; ++m) {
            const int mt = 2 * w + m;
            const f16v& a = (nt == 0) ? (m == 0 ? acc00 : acc01)
                                      : (m == 0 ? acc10 : acc11);
#pragma unroll
            for (int q = 0; q < 4; ++q) {
                const int od = mt * 32 + 8 * q + 4 * hi;
                uint2 u;
                u.x = pack_bf16(a[4 * q + 0], a[4 * q + 1]);
                u.y = pack_bf16(a[4 * q + 2], a[4 * q + 3]);
                *reinterpret_cast<uint2*>(
                    partial + ((size_t)blk * kB + b) * kSeg + od) = u;
            }
        }
    }
}

// Route: per block, both b-halves (nt loop). Phase L -> c in LDS -> phase A.
__device__ void route_body(const unsigned* __restrict__ wPack2,
                           const unsigned* __restrict__ xPack,
                           const float* __restrict__ vsumPack,
                           __hip_bfloat16* __restrict__ partial,
                           float (*Zl)[8][4][32], unsigned (*cl)[16][32])
{
    const int tid = threadIdx.x;
    const int blk = blockIdx.x;
    const int w   = __builtin_amdgcn_readfirstlane(tid >> 6);
    const int l   = tid & 63;
    const int b32 = l & 31;
    const int hi  = l >> 5;

    const int4* wp4 = reinterpret_cast<const int4*>(wPack2);
    const int2* xp2 = reinterpret_cast<const int2*>(xPack);
    const size_t abase = ((size_t)blk * 64 + w) * 64 + l;          // +nn*512

    for (int nt = 0; nt < 2; ++nt) {
        const int b = nt * 32 + b32;
        const size_t xbase = ((size_t)blk * 16 + nt) * 64 + l;     // +nn*128

        // ---- phase L: couplings into LDS ----
        {
            float vsp[2][16];
#pragma unroll
            for (int m = 0; m < 2; ++m) {
                const int mt = 2 * w + m;
                const float4* vp = reinterpret_cast<const float4*>(
                    vsumPack + (((size_t)mt * 2 + hi) * 64 + b) * 16);
#pragma unroll
                for (int k = 0; k < 4; ++k) {
                    const float4 v = vp[k];
                    vsp[m][4 * k + 0] = v.x; vsp[m][4 * k + 1] = v.y;
                    vsp[m][4 * k + 2] = v.z; vsp[m][4 * k + 3] = v.w;
                }
            }

            for (int h = 0; h < 2; ++h) {
                float e[4][4];
#pragma unroll
                for (int k = 0; k < 4; ++k) {
                    const int nn = h * 4 + k;
                    const int4 aw = wp4[abase + (size_t)nn * 512];
                    const int2 bx = xp2[xbase + (size_t)nn * 128];
                    A2 ua0; ua0.i = make_int2(aw.x, aw.y);
                    A2 ua1; ua1.i = make_int2(aw.z, aw.w);
                    A2 ub;  ub.i  = bx;
                    f16v t0, t1;
#pragma unroll
                    for (int r = 0; r < 16; ++r) { t0[r] = 0.0f; t1[r] = 0.0f; }
                    t0 = mfma_32x32x8_bf16(ua0.s, ub.s, t0);
                    t1 = mfma_32x32x8_bf16(ua1.s, ub.s, t1);
                    {
                        float a0_ = fmaf(vsp[0][1], t0[1], vsp[0][0] * t0[0]);
                        float a1_ = fmaf(vsp[0][3], t0[3], vsp[0][2] * t0[2]);
                        float a2_ = fmaf(vsp[0][5], t0[5], vsp[0][4] * t0[4]);
                        float a3_ = fmaf(vsp[0][7], t0[7], vsp[0][6] * t0[6]);
                        float p0 = (a0_ + a1_) + (a2_ + a3_);
                        float b0_ = fmaf(vsp[0][9],  t0[9],  vsp[0][8]  * t0[8]);
                        float b1_ = fmaf(vsp[0][11], t0[11], vsp[0][10] * t0[10]);
                        float b2_ = fmaf(vsp[0][13], t0[13], vsp[0][12] * t0[12]);
                        float b3_ = fmaf(vsp[0][15], t0[15], vsp[0][14] * t0[14]);
                        float p1 = (b0_ + b1_) + (b2_ + b3_);
                        p0 += __shfl_xor(p0, 32);
                        p1 += __shfl_xor(p1, 32);
                        e[k][0] = exp2f(p0); e[k][1] = exp2f(p1);
                    }
                    {
                        float a0_ = fmaf(vsp[1][1], t1[1], vsp[1][0] * t1[0]);
                        float a1_ = fmaf(vsp[1][3], t1[3], vsp[1][2] * t1[2]);
                        float a2_ = fmaf(vsp[1][5], t1[5], vsp[1][4] * t1[4]);
                        float a3_ = fmaf(vsp[1][7], t1[7], vsp[1][6] * t1[6]);
                        float p0 = (a0_ + a1_) + (a2_ + a3_);
                        float b0_ = fmaf(vsp[1][9],  t1[9],  vsp[1][8]  * t1[8]);
                        float b1_ = fmaf(vsp[1][11], t1[11], vsp[1][10] * t1[10]);
                        float b2_ = fmaf(vsp[1][13], t1[13], vsp[1][12] * t1[12]);
                        float b3_ = fmaf(vsp[1][15], t1[15], vsp[1][14] * t1[14]);
                        float p1 = (b0_ + b1_) + (b2_ + b3_);
                        p0 += __shfl_xor(p0, 32);
                        p1 += __shfl_xor(p1, 32);
                        e[k][2] = exp2f(p0); e[k][3] = exp2f(p1);
                    }
                    if (l < 32)
                        Zl[h][w][k][l] = (e[k][0] + e[k][1]) + (e[k][2] + e[k][3]);
                }
                __syncthreads();
#pragma unroll
                for (int k = 0; k < 4; ++k) {
                    float Z = 0.0f;
#pragma unroll
                    for (int w2 = 0; w2 < 8; ++w2) Z += Zl[h][w2][k][b32];
                    const float rz = __builtin_amdgcn_rcpf(Z);
                    if (l < 32) {
                        cl[h * 4 + k][2 * w + 0][l] = pack_bf16(e[k][0] * rz, e[k][1] * rz);
                        cl[h * 4 + k][2 * w + 1][l] = pack_bf16(e[k][2] * rz, e[k][3] * rz);
                    }
                }
            }
        }
        __syncthreads();
        __builtin_amdgcn_sched_barrier(0);   // keep phase-A loads out of phase L

        // ---- phase A: s accumulation (sacc live; vsp dead) ----
        float sacc[2][16];
#pragma unroll
        for (int r = 0; r < 16; ++r) { sacc[0][r] = 0.0f; sacc[1][r] = 0.0f; }

#pragma unroll 2
        for (int nn = 0; nn < kNPer; ++nn) {
            const int4 aw = wp4[abase + (size_t)nn * 512];
            const int2 bx = xp2[xbase + (size_t)nn * 128];
            A2 ua0; ua0.i = make_int2(aw.x, aw.y);
            A2 ua1; ua1.i = make_int2(aw.z, aw.w);
            A2 ub;  ub.i  = bx;
            const unsigned cp0 = cl[nn][2 * w + 0][b32];
            const unsigned cp1 = cl[nn][2 * w + 1][b32];
            f16v t0, t1;
#pragma unroll
            for (int r = 0; r < 16; ++r) { t0[r] = 0.0f; t1[r] = 0.0f; }
            t0 = mfma_32x32x8_bf16(ua0.s, ub.s, t0);
            t1 = mfma_32x32x8_bf16(ua1.s, ub.s, t1);
            const float c00 = bf_lo(cp0), c01 = bf_hi(cp0);
            const float c10 = bf_lo(cp1), c11 = bf_hi(cp1);
#pragma unroll
            for (int r = 0; r < 8; ++r) {
                sacc[0][r]     = fmaf(c00, t0[r],     sacc[0][r]);
                sacc[0][8 + r] = fmaf(c01, t0[8 + r], sacc[0][8 + r]);
                sacc[1][r]     = fmaf(c10, t1[r],     sacc[1][r]);
                sacc[1][8 + r] = fmaf(c11, t1[8 + r], sacc[1][8 + r]);
            }
        }

#pragma unroll
        for (int m = 0; m < 2; ++m) {
            const int mt = 2 * w + m;
#pragma unroll
            for (int q = 0; q < 4; ++q) {
                const int od = mt * 32 + 8 * q + 4 * hi;
                uint2 u;
                u.x = pack_bf16(sacc[m][4 * q + 0], sacc[m][4 * q + 1]);
                u.y = pack_bf16(sacc[m][4 * q + 2], sacc[m][4 * q + 3]);
                *reinterpret_cast<uint2*>(
                    partial + ((size_t)blk * kB + b) * kSeg + od) = u;
            }
        }
        __syncthreads();   // before next nt reuses Zl/cl
    }
}

// Finish: 256 blocks map 1:1 to (b, od-quarter). Vectorized uint2 loads.
__device__ void finish_body(const __hip_bfloat16* __restrict__ partial,
                            float* __restrict__ vsum, float* __restrict__ vsumPack,
                            float* __restrict__ out, int pass,
                            float (*red)[128], float* sq, float* fo)
{
    const int b  = blockIdx.x >> 2;
    const int q  = blockIdx.x & 3;
    const int t  = threadIdx.x;
    const int qd = t & 31;            // od-quad within my 128-od quarter
    const int sg = t >> 5;            // slab group 0..15 (16 slabs each)
    const int od0 = q * 128 + qd * 4;

    const __hip_bfloat16* p = partial
        + ((size_t)(sg * 16) * kB + b) * kSeg + od0;
    float s0 = 0, s1 = 0, s2 = 0, s3 = 0;
#pragma unroll
    for (int k = 0; k < 16; ++k) {
        const uint2 u = *reinterpret_cast<const uint2*>(p + (size_t)k * (kB * kSeg));
        s0 += bf_lo(u.x); s1 += bf_hi(u.x);
        s2 += bf_lo(u.y); s3 += bf_hi(u.y);
    }

    *reinterpret_cast<float4*>(&red[sg][qd * 4]) = make_float4(s0, s1, s2, s3);
    __syncthreads();
    if (t < 128) {
        float s = 0.0f;
#pragma unroll
        for (int g = 0; g < 16; ++g) s += red[g][t];
        if (pass == 0) s *= (1.0f / 32.0f);   // uniform coupling 1/No
        sq[t] = s * s;
        red[0][t] = s;    // own-column reuse
    }
    __syncthreads();
    if (t < 8) {
        float n2 = 0.0f;
#pragma unroll
        for (int d = 0; d < 16; ++d) n2 += sq[t * 16 + d];
        fo[t] = sqrtf(n2) / (1.0f + n2);   // ||s|| / (1 + ||s||^2)
    }
    __syncthreads();
    if (t < 128) {
        const float s = red[0][t];
        const int od = q * 128 + t;
        const float v = fo[t >> 4] * s;
        float nv = v;
        if (pass == 0) {
            vsum[(size_t)b * kSeg + od] = v;
        } else if (pass == 1) {
            nv = vsum[(size_t)b * kSeg + od] + v;
            vsum[(size_t)b * kSeg + od] = nv;
        } else {
            out[(size_t)b * kSeg + od] = v;
        }
        if (pass < 2) {
            const int mt = od >> 5, r5 = od & 31;
            const int hi = (r5 >> 2) & 1, reg = (r5 & 3) | ((r5 >> 3) << 2);
            vsumPack[(((size_t)mt * 2 + hi) * 64 + b) * 16 + reg] =
                nv * 1.44269504f;
        }
    }
    __syncthreads();   // LDS reuse safety before next phase
}

// ---------------------------------------------------------------------------
// The whole pipeline as one cooperative kernel: grid 256 = 1 block/CU
// (co-residency guaranteed), grid.sync() between phases replaces 5 kernel
// boundaries. __launch_bounds__(512,1) -> 256-VGPR cap: merged phases cannot
// spill (each phase's live set <= ~120).
// ---------------------------------------------------------------------------
__global__ __launch_bounds__(512, 1)
void caps_all(const float* __restrict__ xg, const float* __restrict__ Wg,
              unsigned* __restrict__ wPack2, unsigned* __restrict__ xPack,
              __hip_bfloat16* __restrict__ partial, float* __restrict__ vsum,
              float* __restrict__ vsumPack, float* __restrict__ out)
{
    __shared__ float    Zl[2][8][4][32];     // 8 KB   (route)
    __shared__ unsigned cl[kNPer][16][32];   // 16 KB  (route)
    __shared__ float    red[16][128];        // 8 KB   (finish)
    __shared__ float    sq[128];
    __shared__ float    fo[8];

    cg::grid_group grid = cg::this_grid();

    prepacc_body(xg, Wg, wPack2, xPack, partial);
    grid.sync();
    finish_body(partial, vsum, vsumPack, out, 0, red, sq, fo);
    grid.sync();
    route_body(wPack2, xPack, vsumPack, partial, Zl, cl);
    grid.sync();
    finish_body(partial, vsum, vsumPack, out, 1, red, sq, fo);
    grid.sync();
    route_body(wPack2, xPack, vsumPack, partial, Zl, cl);
    grid.sync();
    finish_body(partial, vsum, vsumPack, out, 2, red, sq, fo);
}

// ---------------------------------------------------------------------------
extern "C" void kernel_launch(void* const* d_in, const int* in_sizes, int n_in,
                              void* d_out, int out_size, void* d_ws, size_t ws_size,
                              hipStream_t stream)
{
    const float* x = (const float*)d_in[0];   // (64, 2048, 8)
    const float* W = (const float*)d_in[1];   // (2048, 32, 16, 8)
    float* out = (float*)d_out;               // (64, 32, 16)

    char* base = (char*)d_ws;
    __hip_bfloat16* partial = (__hip_bfloat16*)base;                  // 16.78 MB
    base += (size_t)kSlabs * kB * kSeg * sizeof(__hip_bfloat16);
    float* vsum = (float*)base;                                       // 128 KB
    base += (size_t)kB * kSeg * sizeof(float);
    float* vsumPack = (float*)base;                                   // 128 KB
    base += (size_t)16 * 2 * 64 * 16 * sizeof(float);
    unsigned* wPack2 = (unsigned*)base;                               // 16.78 MB
    base += (size_t)kNi * 16 * 64 * 2 * sizeof(unsigned);
    unsigned* xPack = (unsigned*)base;                                // 2 MB

    void* args[] = { (void*)&x, (void*)&W, (void*)&wPack2, (void*)&xPack,
                     (void*)&partial, (void*)&vsum, (void*)&vsumPack, (void*)&out };
    hipLaunchCooperativeKernel((const void*)caps_all, dim3(kSlabs), dim3(512),
                               args, 0, stream);
}

// Round 16
// 253.609 us; speedup vs baseline: 1.0609x; 1.0609x over previous
//
#include <hip/hip_runtime.h>
#include <hip/hip_bf16.h>
#include <math.h>

namespace {
constexpr int kB  = 64;
constexpr int kNi = 2048;
constexpr int kSeg   = 512;            // od = o*16 + d
constexpr int kSlabs = 256;            // n-slabs = grid = 1 block/CU
constexpr int kNPer  = kNi / kSlabs;   // 8 n per slab
}

typedef __attribute__((ext_vector_type(4)))  short s4;    // 4 bf16 (2 VGPR)
typedef __attribute__((ext_vector_type(16))) float f16v;  // MFMA C/D

__device__ __forceinline__ f16v mfma_32x32x8_bf16(s4 a, s4 b, f16v c) {
#if __has_builtin(__builtin_amdgcn_mfma_f32_32x32x8bf16_1k)
    return __builtin_amdgcn_mfma_f32_32x32x8bf16_1k(a, b, c, 0, 0, 0);
#else
    asm("v_mfma_f32_32x32x8_bf16 %0, %1, %2, %0" : "+v"(c) : "v"(a), "v"(b));
    return c;
#endif
}

__device__ __forceinline__ unsigned pack_bf16(float lo, float hi) {
    union { __hip_bfloat162 h; unsigned u; } v;
    v.h = __float22bfloat162_rn(make_float2(lo, hi));
    return v.u;
}
__device__ __forceinline__ float bf_lo(unsigned u) { return __uint_as_float(u << 16); }
__device__ __forceinline__ float bf_hi(unsigned u) { return __uint_as_float(u & 0xffff0000u); }

union A2 { int2 i; s4 s; };

// ---------------------------------------------------------------------------
// Hand-rolled grid barrier (sense-reversing, device-scope atomics in L3).
// bar[0] = arrive counter, bar[1] = generation. Zeroed per launch via
// hipMemsetAsync. Deadlock-free: grid 256 = 1 block/CU, all co-resident.
// t0 fences are cache-wide (wb/inv act on the CU's L1 and XCD's L2), so they
// release/acquire the whole block's traffic; __syncthreads drains each wave's
// stores to L2 before the release fence. Same mechanism grid.sync uses —
// minus its ~45 us/sync overhead (measured r15).
// ---------------------------------------------------------------------------
__device__ __forceinline__ void gridbar(unsigned* bar, unsigned nb) {
    __syncthreads();
    if (threadIdx.x == 0) {
        __threadfence();   // release: write back this XCD's L2
        unsigned gen = __hip_atomic_load(bar + 1, __ATOMIC_RELAXED,
                                         __HIP_MEMORY_SCOPE_AGENT);
        unsigned prev = __hip_atomic_fetch_add(bar, 1u, __ATOMIC_ACQ_REL,
                                               __HIP_MEMORY_SCOPE_AGENT);
        if (prev == nb - 1u) {
            __hip_atomic_store(bar, 0u, __ATOMIC_RELAXED,
                               __HIP_MEMORY_SCOPE_AGENT);
            __hip_atomic_fetch_add(bar + 1, 1u, __ATOMIC_RELEASE,
                                   __HIP_MEMORY_SCOPE_AGENT);
        } else {
            while (__hip_atomic_load(bar + 1, __ATOMIC_RELAXED,
                                     __HIP_MEMORY_SCOPE_AGENT) == gen)
                __builtin_amdgcn_s_sleep(8);
        }
        __threadfence();   // acquire: invalidate stale L1/L2 lines
    }
    __syncthreads();
}

// C/D layout (m74/m101-verified): col = l&31 (= b),
// row = (reg&3)+8*(reg>>2)+4*(l>>5); regs 0-7 -> o=2mt, regs 8-15 -> o=2mt+1.

// ---------------------------------------------------------------------------
// Phase bodies (r14/r15-verified logic, unchanged).
// ---------------------------------------------------------------------------
__device__ void prepacc_body(const float* __restrict__ xg, const float* __restrict__ Wg,
                             unsigned* __restrict__ wPack2, unsigned* __restrict__ xPack,
                             __hip_bfloat16* __restrict__ partial)
{
    const int tid = threadIdx.x;
    const int blk = blockIdx.x;                    // slab 0..255
    const int w   = __builtin_amdgcn_readfirstlane(tid >> 6);
    const int l   = tid & 63;
    const int o32 = l & 31;
    const int hi  = l >> 5;

    const float4* Wg4 = reinterpret_cast<const float4*>(Wg);
    const float4* xg4 = reinterpret_cast<const float4*>(xg);

    f16v acc00, acc01, acc10, acc11;   // [nt][m], static names (rule #20)
#pragma unroll
    for (int r = 0; r < 16; ++r) {
        acc00[r] = 0.0f; acc01[r] = 0.0f; acc10[r] = 0.0f; acc11[r] = 0.0f;
    }

#pragma unroll 2
    for (int nn = 0; nn < kNPer; ++nn) {
        const int n = blk * kNPer + nn;
        const float4 w0 = Wg4[((size_t)n * 512 + (2 * w + 0) * 32 + o32) * 2 + hi];
        const float4 w1 = Wg4[((size_t)n * 512 + (2 * w + 1) * 32 + o32) * 2 + hi];
        int4 wp;
        wp.x = (int)pack_bf16(w0.x, w0.y);
        wp.y = (int)pack_bf16(w0.z, w0.w);
        wp.z = (int)pack_bf16(w1.x, w1.y);
        wp.w = (int)pack_bf16(w1.z, w1.w);
        reinterpret_cast<int4*>(wPack2)[((size_t)n * 8 + w) * 64 + l] = wp;

        const float4 x0 = xg4[((size_t)(0 * 32 + o32) * kNi + n) * 2 + hi];
        const float4 x1 = xg4[((size_t)(32 + o32) * kNi + n) * 2 + hi];
        uint2 q0, q1;
        q0.x = pack_bf16(x0.x, x0.y); q0.y = pack_bf16(x0.z, x0.w);
        q1.x = pack_bf16(x1.x, x1.y); q1.y = pack_bf16(x1.z, x1.w);
        *reinterpret_cast<uint2*>(xPack + ((size_t)(n * 2 + 0) * 64 + l) * 2) = q0;
        *reinterpret_cast<uint2*>(xPack + ((size_t)(n * 2 + 1) * 64 + l) * 2) = q1;

        A2 a0; a0.i = make_int2(wp.x, wp.y);
        A2 a1; a1.i = make_int2(wp.z, wp.w);
        A2 b0; b0.i = make_int2((int)q0.x, (int)q0.y);
        A2 b1; b1.i = make_int2((int)q1.x, (int)q1.y);
        acc00 = mfma_32x32x8_bf16(a0.s, b0.s, acc00);
        acc01 = mfma_32x32x8_bf16(a1.s, b0.s, acc01);
        acc10 = mfma_32x32x8_bf16(a0.s, b1.s, acc10);
        acc11 = mfma_32x32x8_bf16(a1.s, b1.s, acc11);
    }

#pragma unroll
    for (int nt = 0; nt < 2; ++nt) {
        const int b = nt * 32 + o32;
#pragma unroll
        for (int m = 0; m < 2; ++m) {
            const int mt = 2 * w + m;
            const f16v& a = (nt == 0) ? (m == 0 ? acc00 : acc01)
                                      : (m == 0 ? acc10 : acc11);
#pragma unroll
            for (int q = 0; q < 4; ++q) {
                const int od = mt * 32 + 8 * q + 4 * hi;
                uint2 u;
                u.x = pack_bf16(a[4 * q + 0], a[4 * q + 1]);
                u.y = pack_bf16(a[4 * q + 2], a[4 * q + 3]);
                *reinterpret_cast<uint2*>(
                    partial + ((size_t)blk * kB + b) * kSeg + od) = u;
            }
        }
    }
}

// Route: per block, both b-halves (nt loop). Phase L -> c in LDS -> phase A.
__device__ void route_body(const unsigned* __restrict__ wPack2,
                           const unsigned* __restrict__ xPack,
                           const float* __restrict__ vsumPack,
                           __hip_bfloat16* __restrict__ partial,
                           float (*Zl)[8][4][32], unsigned (*cl)[16][32])
{
    const int tid = threadIdx.x;
    const int blk = blockIdx.x;
    const int w   = __builtin_amdgcn_readfirstlane(tid >> 6);
    const int l   = tid & 63;
    const int b32 = l & 31;
    const int hi  = l >> 5;

    const int4* wp4 = reinterpret_cast<const int4*>(wPack2);
    const int2* xp2 = reinterpret_cast<const int2*>(xPack);
    const size_t abase = ((size_t)blk * 64 + w) * 64 + l;          // +nn*512

    for (int nt = 0; nt < 2; ++nt) {
        const int b = nt * 32 + b32;
        const size_t xbase = ((size_t)blk * 16 + nt) * 64 + l;     // +nn*128

        // ---- phase L: couplings into LDS ----
        {
            float vsp[2][16];
#pragma unroll
            for (int m = 0; m < 2; ++m) {
                const int mt = 2 * w + m;
                const float4* vp = reinterpret_cast<const float4*>(
                    vsumPack + (((size_t)mt * 2 + hi) * 64 + b) * 16);
#pragma unroll
                for (int k = 0; k < 4; ++k) {
                    const float4 v = vp[k];
                    vsp[m][4 * k + 0] = v.x; vsp[m][4 * k + 1] = v.y;
                    vsp[m][4 * k + 2] = v.z; vsp[m][4 * k + 3] = v.w;
                }
            }

            for (int h = 0; h < 2; ++h) {
                float e[4][4];
#pragma unroll
                for (int k = 0; k < 4; ++k) {
                    const int nn = h * 4 + k;
                    const int4 aw = wp4[abase + (size_t)nn * 512];
                    const int2 bx = xp2[xbase + (size_t)nn * 128];
                    A2 ua0; ua0.i = make_int2(aw.x, aw.y);
                    A2 ua1; ua1.i = make_int2(aw.z, aw.w);
                    A2 ub;  ub.i  = bx;
                    f16v t0, t1;
#pragma unroll
                    for (int r = 0; r < 16; ++r) { t0[r] = 0.0f; t1[r] = 0.0f; }
                    t0 = mfma_32x32x8_bf16(ua0.s, ub.s, t0);
                    t1 = mfma_32x32x8_bf16(ua1.s, ub.s, t1);
                    {
                        float a0_ = fmaf(vsp[0][1], t0[1], vsp[0][0] * t0[0]);
                        float a1_ = fmaf(vsp[0][3], t0[3], vsp[0][2] * t0[2]);
                        float a2_ = fmaf(vsp[0][5], t0[5], vsp[0][4] * t0[4]);
                        float a3_ = fmaf(vsp[0][7], t0[7], vsp[0][6] * t0[6]);
                        float p0 = (a0_ + a1_) + (a2_ + a3_);
                        float b0_ = fmaf(vsp[0][9],  t0[9],  vsp[0][8]  * t0[8]);
                        float b1_ = fmaf(vsp[0][11], t0[11], vsp[0][10] * t0[10]);
                        float b2_ = fmaf(vsp[0][13], t0[13], vsp[0][12] * t0[12]);
                        float b3_ = fmaf(vsp[0][15], t0[15], vsp[0][14] * t0[14]);
                        float p1 = (b0_ + b1_) + (b2_ + b3_);
                        p0 += __shfl_xor(p0, 32);
                        p1 += __shfl_xor(p1, 32);
                        e[k][0] = exp2f(p0); e[k][1] = exp2f(p1);
                    }
                    {
                        float a0_ = fmaf(vsp[1][1], t1[1], vsp[1][0] * t1[0]);
                        float a1_ = fmaf(vsp[1][3], t1[3], vsp[1][2] * t1[2]);
                        float a2_ = fmaf(vsp[1][5], t1[5], vsp[1][4] * t1[4]);
                        float a3_ = fmaf(vsp[1][7], t1[7], vsp[1][6] * t1[6]);
                        float p0 = (a0_ + a1_) + (a2_ + a3_);
                        float b0_ = fmaf(vsp[1][9],  t1[9],  vsp[1][8]  * t1[8]);
                        float b1_ = fmaf(vsp[1][11], t1[11], vsp[1][10] * t1[10]);
                        float b2_ = fmaf(vsp[1][13], t1[13], vsp[1][12] * t1[12]);
                        float b3_ = fmaf(vsp[1][15], t1[15], vsp[1][14] * t1[14]);
                        float p1 = (b0_ + b1_) + (b2_ + b3_);
                        p0 += __shfl_xor(p0, 32);
                        p1 += __shfl_xor(p1, 32);
                        e[k][2] = exp2f(p0); e[k][3] = exp2f(p1);
                    }
                    if (l < 32)
                        Zl[h][w][k][l] = (e[k][0] + e[k][1]) + (e[k][2] + e[k][3]);
                }
                __syncthreads();
#pragma unroll
                for (int k = 0; k < 4; ++k) {
                    float Z = 0.0f;
#pragma unroll
                    for (int w2 = 0; w2 < 8; ++w2) Z += Zl[h][w2][k][b32];
                    const float rz = __builtin_amdgcn_rcpf(Z);
                    if (l < 32) {
                        cl[h * 4 + k][2 * w + 0][l] = pack_bf16(e[k][0] * rz, e[k][1] * rz);
                        cl[h * 4 + k][2 * w + 1][l] = pack_bf16(e[k][2] * rz, e[k][3] * rz);
                    }
                }
            }
        }
        __syncthreads();
        __builtin_amdgcn_sched_barrier(0);   // keep phase-A loads out of phase L

        // ---- phase A: s accumulation (sacc live; vsp dead) ----
        float sacc[2][16];
#pragma unroll
        for (int r = 0; r < 16; ++r) { sacc[0][r] = 0.0f; sacc[1][r] = 0.0f; }

#pragma unroll 2
        for (int nn = 0; nn < kNPer; ++nn) {
            const int4 aw = wp4[abase + (size_t)nn * 512];
            const int2 bx = xp2[xbase + (size_t)nn * 128];
            A2 ua0; ua0.i = make_int2(aw.x, aw.y);
            A2 ua1; ua1.i = make_int2(aw.z, aw.w);
            A2 ub;  ub.i  = bx;
            const unsigned cp0 = cl[nn][2 * w + 0][b32];
            const unsigned cp1 = cl[nn][2 * w + 1][b32];
            f16v t0, t1;
#pragma unroll
            for (int r = 0; r < 16; ++r) { t0[r] = 0.0f; t1[r] = 0.0f; }
            t0 = mfma_32x32x8_bf16(ua0.s, ub.s, t0);
            t1 = mfma_32x32x8_bf16(ua1.s, ub.s, t1);
            const float c00 = bf_lo(cp0), c01 = bf_hi(cp0);
            const float c10 = bf_lo(cp1), c11 = bf_hi(cp1);
#pragma unroll
            for (int r = 0; r < 8; ++r) {
                sacc[0][r]     = fmaf(c00, t0[r],     sacc[0][r]);
                sacc[0][8 + r] = fmaf(c01, t0[8 + r], sacc[0][8 + r]);
                sacc[1][r]     = fmaf(c10, t1[r],     sacc[1][r]);
                sacc[1][8 + r] = fmaf(c11, t1[8 + r], sacc[1][8 + r]);
            }
        }

#pragma unroll
        for (int m = 0; m < 2; ++m) {
            const int mt = 2 * w + m;
#pragma unroll
            for (int q = 0; q < 4; ++q) {
                const int od = mt * 32 + 8 * q + 4 * hi;
                uint2 u;
                u.x = pack_bf16(sacc[m][4 * q + 0], sacc[m][4 * q + 1]);
                u.y = pack_bf16(sacc[m][4 * q + 2], sacc[m][4 * q + 3]);
                *reinterpret_cast<uint2*>(
                    partial + ((size_t)blk * kB + b) * kSeg + od) = u;
            }
        }
        __syncthreads();   // before next nt reuses Zl/cl
    }
}

// Finish: 256 blocks map 1:1 to (b, od-quarter). Vectorized uint2 loads.
__device__ void finish_body(const __hip_bfloat16* __restrict__ partial,
                            float* __restrict__ vsum, float* __restrict__ vsumPack,
                            float* __restrict__ out, int pass,
                            float (*red)[128], float* sq, float* fo)
{
    const int b  = blockIdx.x >> 2;
    const int q  = blockIdx.x & 3;
    const int t  = threadIdx.x;
    const int qd = t & 31;            // od-quad within my 128-od quarter
    const int sg = t >> 5;            // slab group 0..15 (16 slabs each)
    const int od0 = q * 128 + qd * 4;

    const __hip_bfloat16* p = partial
        + ((size_t)(sg * 16) * kB + b) * kSeg + od0;
    float s0 = 0, s1 = 0, s2 = 0, s3 = 0;
#pragma unroll
    for (int k = 0; k < 16; ++k) {
        const uint2 u = *reinterpret_cast<const uint2*>(p + (size_t)k * (kB * kSeg));
        s0 += bf_lo(u.x); s1 += bf_hi(u.x);
        s2 += bf_lo(u.y); s3 += bf_hi(u.y);
    }

    *reinterpret_cast<float4*>(&red[sg][qd * 4]) = make_float4(s0, s1, s2, s3);
    __syncthreads();
    if (t < 128) {
        float s = 0.0f;
#pragma unroll
        for (int g = 0; g < 16; ++g) s += red[g][t];
        if (pass == 0) s *= (1.0f / 32.0f);   // uniform coupling 1/No
        sq[t] = s * s;
        red[0][t] = s;    // own-column reuse
    }
    __syncthreads();
    if (t < 8) {
        float n2 = 0.0f;
#pragma unroll
        for (int d = 0; d < 16; ++d) n2 += sq[t * 16 + d];
        fo[t] = sqrtf(n2) / (1.0f + n2);   // ||s|| / (1 + ||s||^2)
    }
    __syncthreads();
    if (t < 128) {
        const float s = red[0][t];
        const int od = q * 128 + t;
        const float v = fo[t >> 4] * s;
        float nv = v;
        if (pass == 0) {
            vsum[(size_t)b * kSeg + od] = v;
        } else if (pass == 1) {
            nv = vsum[(size_t)b * kSeg + od] + v;
            vsum[(size_t)b * kSeg + od] = nv;
        } else {
            out[(size_t)b * kSeg + od] = v;
        }
        if (pass < 2) {
            const int mt = od >> 5, r5 = od & 31;
            const int hi = (r5 >> 2) & 1, reg = (r5 & 3) | ((r5 >> 3) << 2);
            vsumPack[(((size_t)mt * 2 + hi) * 64 + b) * 16 + reg] =
                nv * 1.44269504f;
        }
    }
    __syncthreads();   // LDS reuse safety before next phase
}

// ---------------------------------------------------------------------------
// Whole pipeline, one kernel, hand-rolled grid barriers (5 of them).
// Grid 256 = 1 block/CU, co-residency guaranteed. (512,1) -> 256-VGPR cap:
// merged phases cannot spill (r15 measured 124 VGPR).
// ---------------------------------------------------------------------------
__global__ __launch_bounds__(512, 1)
void caps_all(const float* __restrict__ xg, const float* __restrict__ Wg,
              unsigned* __restrict__ wPack2, unsigned* __restrict__ xPack,
              __hip_bfloat16* __restrict__ partial, float* __restrict__ vsum,
              float* __restrict__ vsumPack, float* __restrict__ out,
              unsigned* __restrict__ bar)
{
    __shared__ float    Zl[2][8][4][32];     // 8 KB   (route)
    __shared__ unsigned cl[kNPer][16][32];   // 16 KB  (route)
    __shared__ float    red[16][128];        // 8 KB   (finish)
    __shared__ float    sq[128];
    __shared__ float    fo[8];

    prepacc_body(xg, Wg, wPack2, xPack, partial);
    gridbar(bar, kSlabs);
    finish_body(partial, vsum, vsumPack, out, 0, red, sq, fo);
    gridbar(bar, kSlabs);
    route_body(wPack2, xPack, vsumPack, partial, Zl, cl);
    gridbar(bar, kSlabs);
    finish_body(partial, vsum, vsumPack, out, 1, red, sq, fo);
    gridbar(bar, kSlabs);
    route_body(wPack2, xPack, vsumPack, partial, Zl, cl);
    gridbar(bar, kSlabs);
    finish_body(partial, vsum, vsumPack, out, 2, red, sq, fo);
}

// ---------------------------------------------------------------------------
extern "C" void kernel_launch(void* const* d_in, const int* in_sizes, int n_in,
                              void* d_out, int out_size, void* d_ws, size_t ws_size,
                              hipStream_t stream)
{
    const float* x = (const float*)d_in[0];   // (64, 2048, 8)
    const float* W = (const float*)d_in[1];   // (2048, 32, 16, 8)
    float* out = (float*)d_out;               // (64, 32, 16)

    char* base = (char*)d_ws;
    __hip_bfloat16* partial = (__hip_bfloat16*)base;                  // 16.78 MB
    base += (size_t)kSlabs * kB * kSeg * sizeof(__hip_bfloat16);
    float* vsum = (float*)base;                                       // 128 KB
    base += (size_t)kB * kSeg * sizeof(float);
    float* vsumPack = (float*)base;                                   // 128 KB
    base += (size_t)16 * 2 * 64 * 16 * sizeof(float);
    unsigned* wPack2 = (unsigned*)base;                               // 16.78 MB
    base += (size_t)kNi * 16 * 64 * 2 * sizeof(unsigned);
    unsigned* xPack = (unsigned*)base;                                // 2 MB
    base += (size_t)kNi * 2 * 64 * 4 * sizeof(unsigned);
    unsigned* bar = (unsigned*)base;                                  // 8 B

    hipMemsetAsync(bar, 0, 2 * sizeof(unsigned), stream);

    caps_all<<<dim3(kSlabs), dim3(512), 0, stream>>>(
        x, W, wPack2, xPack, partial, vsum, vsumPack, out, bar);
}

// Round 17
// 72.463 us; speedup vs baseline: 3.7128x; 3.4998x over previous
//
#include <hip/hip_runtime.h>
#include <hip/hip_bf16.h>
#include <math.h>

namespace {
constexpr int kB  = 64;
constexpr int kNi = 2048;
constexpr int kSeg   = 512;            // od = o*16 + d
constexpr int kSlabs = 256;            // n-slabs
constexpr int kNPer  = kNi / kSlabs;   // 8 n per slab
}

typedef __attribute__((ext_vector_type(4)))  short s4;    // 4 bf16 (2 VGPR)
typedef __attribute__((ext_vector_type(16))) float f16v;  // MFMA C/D

__device__ __forceinline__ f16v mfma_32x32x8_bf16(s4 a, s4 b, f16v c) {
#if __has_builtin(__builtin_amdgcn_mfma_f32_32x32x8bf16_1k)
    return __builtin_amdgcn_mfma_f32_32x32x8bf16_1k(a, b, c, 0, 0, 0);
#else
    asm("v_mfma_f32_32x32x8_bf16 %0, %1, %2, %0" : "+v"(c) : "v"(a), "v"(b));
    return c;
#endif
}

__device__ __forceinline__ unsigned pack_bf16(float lo, float hi) {
    union { __hip_bfloat162 h; unsigned u; } v;
    v.h = __float22bfloat162_rn(make_float2(lo, hi));
    return v.u;
}
__device__ __forceinline__ float bf_lo(unsigned u) { return __uint_as_float(u << 16); }
__device__ __forceinline__ float bf_hi(unsigned u) { return __uint_as_float(u & 0xffff0000u); }

union A2 { int2 i; s4 s; };

// C/D layout (m74/m101-verified): col = l&31 (= b),
// row = (reg&3)+8*(reg>>2)+4*(l>>5); regs 0-7 -> o=2mt, regs 8-15 -> o=2mt+1.

// ---------------------------------------------------------------------------
// Fused prep + pass-0, nt-split for occupancy. Grid 512 = slab x b-half.
// Blocks (k, k+256) share the same W slab AND XCD (256 % 8 == 0) -> the
// second W f32 read is an L2 hit; HBM-compulsory traffic unchanged.
// Wave w owns mt {2w, 2w+1} for ITS b-half only: acc = 2 f16v (32 VGPR),
// live ~70 -> 2 blocks/CU, 4 waves/SIMD for this memory-streaming phase.
// nt=0 writes wPack2; xPack/partial writes disjoint per nt.
// Uniform coupling: 1/32 applied in finish<0>.
// ---------------------------------------------------------------------------
__global__ __launch_bounds__(512, 2)
void caps_prepacc(const float* __restrict__ xg, const float* __restrict__ Wg,
                  unsigned* __restrict__ wPack2, unsigned* __restrict__ xPack,
                  __hip_bfloat16* __restrict__ partial)
{
    const int tid = threadIdx.x;
    const int blk = blockIdx.x & (kSlabs - 1);     // slab
    const int nt  = blockIdx.x >> 8;               // b-half
    const int w   = __builtin_amdgcn_readfirstlane(tid >> 6);
    const int l   = tid & 63;
    const int o32 = l & 31;
    const int hi  = l >> 5;
    const int b   = nt * 32 + o32;

    const float4* Wg4 = reinterpret_cast<const float4*>(Wg);
    const float4* xg4 = reinterpret_cast<const float4*>(xg);

    f16v acc0, acc1;                  // my nt's two m-tiles
#pragma unroll
    for (int r = 0; r < 16; ++r) { acc0[r] = 0.0f; acc1[r] = 0.0f; }

#pragma unroll 2
    for (int nn = 0; nn < kNPer; ++nn) {
        const int n = blk * kNPer + nn;
        const float4 w0 = Wg4[((size_t)n * 512 + (2 * w + 0) * 32 + o32) * 2 + hi];
        const float4 w1 = Wg4[((size_t)n * 512 + (2 * w + 1) * 32 + o32) * 2 + hi];
        int4 wp;
        wp.x = (int)pack_bf16(w0.x, w0.y);
        wp.y = (int)pack_bf16(w0.z, w0.w);
        wp.z = (int)pack_bf16(w1.x, w1.y);
        wp.w = (int)pack_bf16(w1.z, w1.w);
        if (nt == 0)
            reinterpret_cast<int4*>(wPack2)[((size_t)n * 8 + w) * 64 + l] = wp;

        const float4 x0 = xg4[((size_t)b * kNi + n) * 2 + hi];
        uint2 q0;
        q0.x = pack_bf16(x0.x, x0.y); q0.y = pack_bf16(x0.z, x0.w);
        *reinterpret_cast<uint2*>(xPack + ((size_t)(n * 2 + nt) * 64 + l) * 2) = q0;

        A2 a0; a0.i = make_int2(wp.x, wp.y);
        A2 a1; a1.i = make_int2(wp.z, wp.w);
        A2 b0; b0.i = make_int2((int)q0.x, (int)q0.y);
        acc0 = mfma_32x32x8_bf16(a0.s, b0.s, acc0);
        acc1 = mfma_32x32x8_bf16(a1.s, b0.s, acc1);
    }

    // partial[slab][b][od] bf16 (my nt's 32 b only)
#pragma unroll
    for (int m = 0; m < 2; ++m) {
        const int mt = 2 * w + m;
        const f16v& a = (m == 0) ? acc0 : acc1;
#pragma unroll
        for (int q = 0; q < 4; ++q) {
            const int od = mt * 32 + 8 * q + 4 * hi;
            uint2 u;
            u.x = pack_bf16(a[4 * q + 0], a[4 * q + 1]);
            u.y = pack_bf16(a[4 * q + 2], a[4 * q + 3]);
            *reinterpret_cast<uint2*>(
                partial + ((size_t)blk * kB + b) * kSeg + od) = u;
        }
    }
}

// ---------------------------------------------------------------------------
// Fused routing iteration (r13/r14-verified, unchanged): phase L (logits -> c
// in LDS) then phase A (accumulate). Sequential register profiles -> no spill.
// ---------------------------------------------------------------------------
__global__ __launch_bounds__(512, 2)
void caps_routef(const unsigned* __restrict__ wPack2, const unsigned* __restrict__ xPack,
                 const float* __restrict__ vsumPack, __hip_bfloat16* __restrict__ partial)
{
    __shared__ float Zl[2][8][4][32];       // 8 KB
    __shared__ unsigned cl[kNPer][16][32];  // 16 KB

    const int tid = threadIdx.x;
    const int blk = blockIdx.x & (kSlabs - 1);
    const int nt  = blockIdx.x >> 8;
    const int w   = __builtin_amdgcn_readfirstlane(tid >> 6);
    const int l   = tid & 63;
    const int b32 = l & 31;
    const int b   = nt * 32 + b32;
    const int hi  = l >> 5;

    const int4* wp4 = reinterpret_cast<const int4*>(wPack2);
    const int2* xp2 = reinterpret_cast<const int2*>(xPack);
    const size_t abase = ((size_t)blk * 64 + w) * 64 + l;          // +nn*512
    const size_t xbase = ((size_t)blk * 16 + nt) * 64 + l;         // +nn*128

    // ---- phase L: couplings into LDS ----
    {
        float vsp[2][16];
#pragma unroll
        for (int m = 0; m < 2; ++m) {
            const int mt = 2 * w + m;
            const float4* vp = reinterpret_cast<const float4*>(
                vsumPack + (((size_t)mt * 2 + hi) * 64 + b) * 16);
#pragma unroll
            for (int k = 0; k < 4; ++k) {
                const float4 v = vp[k];
                vsp[m][4 * k + 0] = v.x; vsp[m][4 * k + 1] = v.y;
                vsp[m][4 * k + 2] = v.z; vsp[m][4 * k + 3] = v.w;
            }
        }

        for (int h = 0; h < 2; ++h) {
            float e[4][4];
#pragma unroll
            for (int k = 0; k < 4; ++k) {
                const int nn = h * 4 + k;
                const int4 aw = wp4[abase + (size_t)nn * 512];
                const int2 bx = xp2[xbase + (size_t)nn * 128];
                A2 ua0; ua0.i = make_int2(aw.x, aw.y);
                A2 ua1; ua1.i = make_int2(aw.z, aw.w);
                A2 ub;  ub.i  = bx;
                f16v t0, t1;
#pragma unroll
                for (int r = 0; r < 16; ++r) { t0[r] = 0.0f; t1[r] = 0.0f; }
                t0 = mfma_32x32x8_bf16(ua0.s, ub.s, t0);
                t1 = mfma_32x32x8_bf16(ua1.s, ub.s, t1);
                {
                    float a0_ = fmaf(vsp[0][1], t0[1], vsp[0][0] * t0[0]);
                    float a1_ = fmaf(vsp[0][3], t0[3], vsp[0][2] * t0[2]);
                    float a2_ = fmaf(vsp[0][5], t0[5], vsp[0][4] * t0[4]);
                    float a3_ = fmaf(vsp[0][7], t0[7], vsp[0][6] * t0[6]);
                    float p0 = (a0_ + a1_) + (a2_ + a3_);
                    float b0_ = fmaf(vsp[0][9],  t0[9],  vsp[0][8]  * t0[8]);
                    float b1_ = fmaf(vsp[0][11], t0[11], vsp[0][10] * t0[10]);
                    float b2_ = fmaf(vsp[0][13], t0[13], vsp[0][12] * t0[12]);
                    float b3_ = fmaf(vsp[0][15], t0[15], vsp[0][14] * t0[14]);
                    float p1 = (b0_ + b1_) + (b2_ + b3_);
                    p0 += __shfl_xor(p0, 32);
                    p1 += __shfl_xor(p1, 32);
                    e[k][0] = exp2f(p0); e[k][1] = exp2f(p1);
                }
                {
                    float a0_ = fmaf(vsp[1][1], t1[1], vsp[1][0] * t1[0]);
                    float a1_ = fmaf(vsp[1][3], t1[3], vsp[1][2] * t1[2]);
                    float a2_ = fmaf(vsp[1][5], t1[5], vsp[1][4] * t1[4]);
                    float a3_ = fmaf(vsp[1][7], t1[7], vsp[1][6] * t1[6]);
                    float p0 = (a0_ + a1_) + (a2_ + a3_);
                    float b0_ = fmaf(vsp[1][9],  t1[9],  vsp[1][8]  * t1[8]);
                    float b1_ = fmaf(vsp[1][11], t1[11], vsp[1][10] * t1[10]);
                    float b2_ = fmaf(vsp[1][13], t1[13], vsp[1][12] * t1[12]);
                    float b3_ = fmaf(vsp[1][15], t1[15], vsp[1][14] * t1[14]);
                    float p1 = (b0_ + b1_) + (b2_ + b3_);
                    p0 += __shfl_xor(p0, 32);
                    p1 += __shfl_xor(p1, 32);
                    e[k][2] = exp2f(p0); e[k][3] = exp2f(p1);
                }
                if (l < 32)
                    Zl[h][w][k][l] = (e[k][0] + e[k][1]) + (e[k][2] + e[k][3]);
            }
            __syncthreads();
#pragma unroll
            for (int k = 0; k < 4; ++k) {
                float Z = 0.0f;
#pragma unroll
                for (int w2 = 0; w2 < 8; ++w2) Z += Zl[h][w2][k][b32];
                const float rz = __builtin_amdgcn_rcpf(Z);
                if (l < 32) {
                    cl[h * 4 + k][2 * w + 0][l] = pack_bf16(e[k][0] * rz, e[k][1] * rz);
                    cl[h * 4 + k][2 * w + 1][l] = pack_bf16(e[k][2] * rz, e[k][3] * rz);
                }
            }
        }
    }
    __syncthreads();
    __builtin_amdgcn_sched_barrier(0);   // keep phase-A loads out of phase L

    // ---- phase A: s accumulation (sacc live; vsp dead) ----
    float sacc[2][16];
#pragma unroll
    for (int r = 0; r < 16; ++r) { sacc[0][r] = 0.0f; sacc[1][r] = 0.0f; }

#pragma unroll 2
    for (int nn = 0; nn < kNPer; ++nn) {
        const int4 aw = wp4[abase + (size_t)nn * 512];
        const int2 bx = xp2[xbase + (size_t)nn * 128];
        A2 ua0; ua0.i = make_int2(aw.x, aw.y);
        A2 ua1; ua1.i = make_int2(aw.z, aw.w);
        A2 ub;  ub.i  = bx;
        const unsigned cp0 = cl[nn][2 * w + 0][b32];
        const unsigned cp1 = cl[nn][2 * w + 1][b32];
        f16v t0, t1;
#pragma unroll
        for (int r = 0; r < 16; ++r) { t0[r] = 0.0f; t1[r] = 0.0f; }
        t0 = mfma_32x32x8_bf16(ua0.s, ub.s, t0);
        t1 = mfma_32x32x8_bf16(ua1.s, ub.s, t1);
        const float c00 = bf_lo(cp0), c01 = bf_hi(cp0);
        const float c10 = bf_lo(cp1), c11 = bf_hi(cp1);
#pragma unroll
        for (int r = 0; r < 8; ++r) {
            sacc[0][r]     = fmaf(c00, t0[r],     sacc[0][r]);
            sacc[0][8 + r] = fmaf(c01, t0[8 + r], sacc[0][8 + r]);
            sacc[1][r]     = fmaf(c10, t1[r],     sacc[1][r]);
            sacc[1][8 + r] = fmaf(c11, t1[8 + r], sacc[1][8 + r]);
        }
    }

    // partial[slab][b][od] bf16
#pragma unroll
    for (int m = 0; m < 2; ++m) {
        const int mt = 2 * w + m;
#pragma unroll
        for (int q = 0; q < 4; ++q) {
            const int od = mt * 32 + 8 * q + 4 * hi;
            uint2 u;
            u.x = pack_bf16(sacc[m][4 * q + 0], sacc[m][4 * q + 1]);
            u.y = pack_bf16(sacc[m][4 * q + 2], sacc[m][4 * q + 3]);
            *reinterpret_cast<uint2*>(
                partial + ((size_t)blk * kB + b) * kSeg + od) = u;
        }
    }
}

// ---------------------------------------------------------------------------
// Finish (r14-verified, unchanged): vectorized uint2 loads, 16-group LDS
// tree -> squash -> vsum/vsumPack/out.
// ---------------------------------------------------------------------------
template<int PASS>
__global__ __launch_bounds__(512, 2)
void caps_finish(const __hip_bfloat16* __restrict__ partial,
                 float* __restrict__ vsum, float* __restrict__ vsumPack,
                 float* __restrict__ out)
{
    const int b  = blockIdx.x >> 2;
    const int q  = blockIdx.x & 3;
    const int t  = threadIdx.x;
    const int qd = t & 31;            // od-quad within my 128-od quarter
    const int sg = t >> 5;            // slab group 0..15 (16 slabs each)
    const int od0 = q * 128 + qd * 4;

    const __hip_bfloat16* p = partial
        + ((size_t)(sg * 16) * kB + b) * kSeg + od0;
    float s0 = 0, s1 = 0, s2 = 0, s3 = 0;
#pragma unroll
    for (int k = 0; k < 16; ++k) {
        const uint2 u = *reinterpret_cast<const uint2*>(p + (size_t)k * (kB * kSeg));
        s0 += bf_lo(u.x); s1 += bf_hi(u.x);
        s2 += bf_lo(u.y); s3 += bf_hi(u.y);
    }

    __shared__ float red[16][128];
    __shared__ float sq[128];
    __shared__ float fo[8];
    *reinterpret_cast<float4*>(&red[sg][qd * 4]) = make_float4(s0, s1, s2, s3);
    __syncthreads();
    if (t < 128) {
        float s = 0.0f;
#pragma unroll
        for (int g = 0; g < 16; ++g) s += red[g][t];
        if (PASS == 0) s *= (1.0f / 32.0f);   // uniform coupling 1/No
        sq[t] = s * s;
        red[0][t] = s;    // own-column reuse
    }
    __syncthreads();
    if (t < 8) {
        float n2 = 0.0f;
#pragma unroll
        for (int d = 0; d < 16; ++d) n2 += sq[t * 16 + d];
        fo[t] = sqrtf(n2) / (1.0f + n2);   // ||s|| / (1 + ||s||^2)
    }
    __syncthreads();
    if (t < 128) {
        const float s = red[0][t];
        const int od = q * 128 + t;
        const float v = fo[t >> 4] * s;
        float nv = v;
        if (PASS == 0) {
            vsum[(size_t)b * kSeg + od] = v;
        } else if (PASS == 1) {
            nv = vsum[(size_t)b * kSeg + od] + v;
            vsum[(size_t)b * kSeg + od] = nv;
        } else {
            out[(size_t)b * kSeg + od] = v;
        }
        if (PASS < 2) {
            // invert C-row map: row = (reg&3) + 8*(reg>>2) + 4*hi
            const int mt = od >> 5, r5 = od & 31;
            const int hi = (r5 >> 2) & 1, reg = (r5 & 3) | ((r5 >> 3) << 2);
            vsumPack[(((size_t)mt * 2 + hi) * 64 + b) * 16 + reg] =
                nv * 1.44269504f;
        }
    }
}

// ---------------------------------------------------------------------------
extern "C" void kernel_launch(void* const* d_in, const int* in_sizes, int n_in,
                              void* d_out, int out_size, void* d_ws, size_t ws_size,
                              hipStream_t stream)
{
    const float* x = (const float*)d_in[0];   // (64, 2048, 8)
    const float* W = (const float*)d_in[1];   // (2048, 32, 16, 8)
    float* out = (float*)d_out;               // (64, 32, 16)

    char* base = (char*)d_ws;
    __hip_bfloat16* partial = (__hip_bfloat16*)base;                  // 16.78 MB
    base += (size_t)kSlabs * kB * kSeg * sizeof(__hip_bfloat16);
    float* vsum = (float*)base;                                       // 128 KB
    base += (size_t)kB * kSeg * sizeof(float);
    float* vsumPack = (float*)base;                                   // 128 KB
    base += (size_t)16 * 2 * 64 * 16 * sizeof(float);
    unsigned* wPack2 = (unsigned*)base;                               // 16.78 MB
    base += (size_t)kNi * 16 * 64 * 2 * sizeof(unsigned);
    unsigned* xPack = (unsigned*)base;                                // 2 MB

    const dim3 gp(kSlabs * 2), bp(512);
    const dim3 gr(kSlabs * 2), br(512);
    const dim3 gf(kB * 4), bf(512);

    caps_prepacc<<<gp, bp, 0, stream>>>(x, W, wPack2, xPack, partial);
    caps_finish<0><<<gf, bf, 0, stream>>>(partial, vsum, vsumPack, out);
    caps_routef<<<gr, br, 0, stream>>>(wPack2, xPack, vsumPack, partial);
    caps_finish<1><<<gf, bf, 0, stream>>>(partial, vsum, vsumPack, out);
    caps_routef<<<gr, br, 0, stream>>>(wPack2, xPack, vsumPack, partial);
    caps_finish<2><<<gf, bf, 0, stream>>>(partial, vsum, vsumPack, out);
}